// Round 1
// baseline (138.847 us; speedup 1.0000x reference)
//
#include <hip/hip_runtime.h>
#include <math.h>

#ifndef M_PI
#define M_PI 3.14159265358979323846
#endif

constexpr float CUT = 5.0f;
constexpr int NY = 16;          // 1+3+5+7 spherical harmonics
constexpr int NRAD = 66;        // 21+18+15+12 radial basis
constexpr int FEAT = NY + NRAD; // 82
constexpr int FSTRIDE = 88;     // 82 features + 4 species + 2 pad
constexpr int NPAIR = 234;      // 21 + 54 + 75 + 84 (m,n) pairs
constexpr int OUTF = 936;       // NPAIR * 4 species
constexpr int ECHUNK = 16;

__global__ void zero_counts_k(int* counts, int A){
  int t = blockIdx.x*blockDim.x + threadIdx.x;
  if (t < A) counts[t] = 0;
}

__global__ void count_k(const int* __restrict__ seg, int P, int* __restrict__ counts){
  int p = blockIdx.x*blockDim.x + threadIdx.x;
  if (p < P) atomicAdd(&counts[seg[p]], 1);
}

// Single-block exclusive scan over A counts -> offsets (and a working copy in cursor).
__global__ __launch_bounds__(1024) void scan_k(const int* __restrict__ counts, int A,
                                               int* __restrict__ offsets, int* __restrict__ cursor){
  __shared__ int sums[1024];
  int t = threadIdx.x;
  int per = (A + 1023) >> 10;       // elements per thread (8 for A=8192)
  int base = t * per;
  int local[32];
  int s = 0;
  #pragma unroll
  for (int k = 0; k < 32; ++k){
    if (k < per){
      int c = (base + k < A) ? counts[base + k] : 0;
      local[k] = s; s += c;
    }
  }
  sums[t] = s;
  __syncthreads();
  for (int off = 1; off < 1024; off <<= 1){
    int v = (t >= off) ? sums[t - off] : 0;
    __syncthreads();
    sums[t] += v;
    __syncthreads();
  }
  int excl = (t == 0) ? 0 : sums[t-1];
  #pragma unroll
  for (int k = 0; k < 32; ++k){
    if (k < per && base + k < A){
      int o = excl + local[k];
      offsets[base+k] = o;
      cursor[base+k]  = o;
    }
  }
}

__global__ void scatter_k(const int* __restrict__ seg, int P,
                          int* __restrict__ cursor, int* __restrict__ sorted){
  int p = blockIdx.x*blockDim.x + threadIdx.x;
  if (p < P){
    int a = seg[p];
    int pos = atomicAdd(&cursor[a], 1);
    sorted[pos] = p;
  }
}

__device__ __forceinline__ float Yval(int j, float x, float y, float z){
  float x2 = x*x, y2 = y*y, z2 = z*z;
  switch (j){
    case 0:  return 0.28209479177387814f;
    case 1:  return 0.4886025119029199f*y;
    case 2:  return 0.4886025119029199f*z;
    case 3:  return 0.4886025119029199f*x;
    case 4:  return 1.0925484305920792f*x*y;
    case 5:  return 1.0925484305920792f*y*z;
    case 6:  return 0.31539156525252005f*(3.0f*z2 - 1.0f);
    case 7:  return 1.0925484305920792f*x*z;
    case 8:  return 0.5462742152960396f*(x2 - y2);
    case 9:  return 0.5900435899266435f*y*(3.0f*x2 - y2);
    case 10: return 2.890611442640554f*x*y*z;
    case 11: return 0.4570457994644658f*y*(5.0f*z2 - 1.0f);
    case 12: return 0.3731763325901154f*z*(5.0f*z2 - 3.0f);
    case 13: return 0.4570457994644658f*x*(5.0f*z2 - 1.0f);
    case 14: return 1.445305721320277f*z*(x2 - y2);
    default: return 0.5900435899266435f*x*(x2 - 3.0f*y2);
  }
}

__global__ __launch_bounds__(256) void accum_k(
    const float* __restrict__ R, const int* __restrict__ Z,
    const float* __restrict__ W, const int* __restrict__ sorted,
    const int* __restrict__ offsets, const int* __restrict__ counts,
    float* __restrict__ out)
{
  int atom = blockIdx.x;
  int t = threadIdx.x;
  int start = offsets[atom];
  int cnt = counts[atom];

  __shared__ float feat[ECHUNK][FSTRIDE]; // [0..15]=Y, [16..81]=rad, [82..85]=species
  __shared__ float esc[ECHUNK][8];        // ux,uy,uz,-,fcut,sin_arg_step,d/CUT

  // Each thread t < 234 owns one (l,m,n) pair, all 4 species channels.
  bool active = (t < NPAIR);
  int yi = 0, ri = 0, ob = 0;
  if (active){
    int q = t;
    if (q < 21){                       // l=0: 1x21
      yi = 0; ri = NY + q; ob = q*4;
    } else if (q < 75){                // l=1: 3x18
      int r = q - 21; int m = r/18; int n = r - m*18;
      yi = 1 + m; ri = NY + 21 + n; ob = 84 + r*4;
    } else if (q < 150){               // l=2: 5x15
      int r = q - 75; int m = r/15; int n = r - m*15;
      yi = 4 + m; ri = NY + 39 + n; ob = 300 + r*4;
    } else {                           // l=3: 7x12
      int r = q - 150; int m = r/12; int n = r - m*12;
      yi = 9 + m; ri = NY + 54 + n; ob = 600 + r*4;
    }
  }

  float a0 = 0.f, a1 = 0.f, a2 = 0.f, a3 = 0.f;

  for (int c0 = 0; c0 < cnt; c0 += ECHUNK){
    int nc = min(ECHUNK, cnt - c0);

    // Phase 0: per-edge scalars + species row
    if (t < nc){
      int e = sorted[start + c0 + t];
      float rx = R[3*e+0], ry = R[3*e+1], rz = R[3*e+2];
      float d = sqrtf(rx*rx + ry*ry + rz*rz + 1e-12f);
      float inv = 1.0f / d;
      esc[t][0] = rx*inv; esc[t][1] = ry*inv; esc[t][2] = rz*inv;
      float dc = fminf(d, CUT);
      esc[t][4] = 0.5f*(cosf((float)M_PI * dc / CUT) + 1.0f);  // fcut
      esc[t][5] = d * ((float)M_PI / CUT);                     // arg per n=1
      esc[t][6] = d * (1.0f / CUT);                            // base for (d/C)^l
      int zs = Z[e];
      float4 w = *reinterpret_cast<const float4*>(W + 4*zs);
      feat[t][82] = w.x; feat[t][83] = w.y; feat[t][84] = w.z; feat[t][85] = w.w;
    }
    __syncthreads();

    // Phase 1: shared features (16 Y + 66 radial per edge)
    for (int f = t; f < nc*FEAT; f += 256){
      int c = f / FEAT; int j = f - c*FEAT;
      float v;
      if (j < NY){
        v = Yval(j, esc[c][0], esc[c][1], esc[c][2]);
      } else {
        int nf = j - NY;
        int l, n;
        if (nf < 21){ l = 0; n = nf; }
        else if (nf < 39){ l = 1; n = nf - 21; }
        else if (nf < 54){ l = 2; n = nf - 39; }
        else { l = 3; n = nf - 54; }
        float arg = esc[c][5] * (float)(n + 1);
        float sv = sinf(arg) / (arg + 1e-6f);
        float b = esc[c][6];
        float p = 1.0f;
        if (l >= 1) p = b;
        if (l >= 2) p *= b;
        if (l == 3) p *= b;
        v = sv * p * esc[c][4];
      }
      feat[c][j] = v;
    }
    __syncthreads();

    // Phase 2: register accumulation, 2 LDS reads + 4 FMA per edge
    if (active){
      for (int c = 0; c < nc; ++c){
        float yr = feat[c][yi] * feat[c][ri];
        a0 = fmaf(yr, feat[c][82], a0);
        a1 = fmaf(yr, feat[c][83], a1);
        a2 = fmaf(yr, feat[c][84], a2);
        a3 = fmaf(yr, feat[c][85], a3);
      }
    }
    __syncthreads();
  }

  if (active){
    float4 o = make_float4(a0, a1, a2, a3);
    *reinterpret_cast<float4*>(out + (size_t)atom*OUTF + ob) = o;
  }
}

extern "C" void kernel_launch(void* const* d_in, const int* in_sizes, int n_in,
                              void* d_out, int out_size, void* d_ws, size_t ws_size,
                              hipStream_t stream)
{
  const float* R  = (const float*)d_in[0];
  const int* seg  = (const int*)d_in[1];
  const int* Z    = (const int*)d_in[2];
  const float* W  = (const float*)d_in[3];
  float* out = (float*)d_out;

  int P = in_sizes[0] / 3;
  int A = out_size / OUTF;

  int* counts  = (int*)d_ws;
  int* offsets = counts + A;
  int* cursor  = offsets + A;
  int* sorted  = cursor + A;

  zero_counts_k<<<(A + 255)/256, 256, 0, stream>>>(counts, A);
  count_k<<<(P + 255)/256, 256, 0, stream>>>(seg, P, counts);
  scan_k<<<1, 1024, 0, stream>>>(counts, A, offsets, cursor);
  scatter_k<<<(P + 255)/256, 256, 0, stream>>>(seg, P, cursor, sorted);
  accum_k<<<A, 256, 0, stream>>>(R, Z, W, sorted, offsets, counts, out);
}

// Round 2
// 68.020 us; speedup vs baseline: 2.0413x; 2.0413x over previous
//
#include <hip/hip_runtime.h>
#include <math.h>

constexpr float CUT = 5.0f;
constexpr float PI_F = 3.14159265358979323846f;
constexpr int OUTF = 936;
constexpr int ECH = 32;   // edges per chunk
constexpr int FR  = 44;   // feat row stride (floats): [0..15]=Y', [16..39]=sv(21+3 pad), [40..43]=w

__global__ void count_k(const int* __restrict__ seg, int P, int* __restrict__ counts){
  int p = blockIdx.x*blockDim.x + threadIdx.x;
  if (p < P) atomicAdd(&counts[seg[p]], 1);
}

// Single-block exclusive scan over A counts -> offsets (and working copy in cursor).
__global__ __launch_bounds__(1024) void scan_k(const int* __restrict__ counts, int A,
                                               int* __restrict__ offsets, int* __restrict__ cursor){
  __shared__ int sums[1024];
  int t = threadIdx.x;
  int per = (A + 1023) >> 10;
  int base = t * per;
  int local[32];
  int s = 0;
  #pragma unroll
  for (int k = 0; k < 32; ++k){
    if (k < per){
      int c = (base + k < A) ? counts[base + k] : 0;
      local[k] = s; s += c;
    }
  }
  sums[t] = s;
  __syncthreads();
  for (int off = 1; off < 1024; off <<= 1){
    int v = (t >= off) ? sums[t - off] : 0;
    __syncthreads();
    sums[t] += v;
    __syncthreads();
  }
  int excl = (t == 0) ? 0 : sums[t-1];
  #pragma unroll
  for (int k = 0; k < 32; ++k){
    if (k < per && base + k < A){
      int o = excl + local[k];
      offsets[base+k] = o;
      cursor[base+k]  = o;
    }
  }
}

__global__ void scatter_k(const int* __restrict__ seg, int P,
                          int* __restrict__ cursor, int* __restrict__ sorted){
  int p = blockIdx.x*blockDim.x + threadIdx.x;
  if (p < P){
    int a = seg[p];
    int pos = atomicAdd(&cursor[a], 1);
    sorted[pos] = p;
  }
}

__global__ __launch_bounds__(64) void accum_k(
    const float* __restrict__ R, const int* __restrict__ Z,
    const float* __restrict__ W, const int* __restrict__ sorted,
    const int* __restrict__ offsets, const int* __restrict__ counts,
    float* __restrict__ out)
{
  int atom = blockIdx.x;
  int t = threadIdx.x;
  int start = offsets[atom];
  int cnt = counts[atom];

  __shared__ float feat[ECH][FR];
  __shared__ float thlds[ECH];

  // Thread -> (l, m, n0) mapping: each active thread owns 4 consecutive n of one m, all 4 s.
  int yi = 0, n0 = 0, ob = 0, nvalid = 0;
  if (t < 62){
    int l, m, r;
    if (t < 6){       l = 0; m = 0;      n0 = 4*t; }
    else if (t < 21){ l = 1; r = t-6;  m = r/5; n0 = 4*(r-5*m); }
    else if (t < 41){ l = 2; r = t-21; m = r/4; n0 = 4*(r-4*m); }
    else {            l = 3; r = t-41; m = r/3; n0 = 4*(r-3*m); }
    const int NLa[4] = {21,18,15,12};
    const int YBa[4] = {0,1,4,9};
    const int OBa[4] = {0,84,300,600};
    int nl = NLa[l];
    yi = YBa[l] + m;
    ob = OBa[l] + (m*nl + n0)*4;
    nvalid = min(4, nl - n0);
  }

  float4 a0 = make_float4(0.f,0.f,0.f,0.f), a1 = a0, a2 = a0, a3 = a0;

  for (int c0 = 0; c0 < cnt; c0 += ECH){
    int nc = min(ECH, cnt - c0);
    __syncthreads();   // protect feat reuse (single-wave block: compiles to waitcnt)

    // ---- Phase 0: one lane per edge: scalars + species + 16 scaled Y values ----
    if (t < nc){
      int e = sorted[start + c0 + t];
      float rx = R[3*e], ry = R[3*e+1], rz = R[3*e+2];
      float d = sqrtf(fmaf(rx,rx, fmaf(ry,ry, rz*rz)) + 1e-12f);
      float inv = __builtin_amdgcn_rcpf(d);
      float ux = rx*inv, uy = ry*inv, uz = rz*inv;
      float th = d * (PI_F/CUT);
      thlds[t] = th;
      float fc = 0.5f*__cosf(fminf(th, PI_F)) + 0.5f;   // == 0.5*(cos(pi*clip(d,0,5)/5)+1)
      float b = d * (1.0f/CUT);
      float p1 = fc*b, p2 = p1*b, p3 = p2*b;
      int zs = Z[e];
      *reinterpret_cast<float4*>(&feat[t][40]) = *reinterpret_cast<const float4*>(W + 4*zs);
      float x2 = ux*ux, y2 = uy*uy, z2 = uz*uz;
      float4 Ya, Yb, Yc, Yd;
      Ya.x = 0.28209479177387814f*fc;
      Ya.y = 0.4886025119029199f*uy*p1;
      Ya.z = 0.4886025119029199f*uz*p1;
      Ya.w = 0.4886025119029199f*ux*p1;
      Yb.x = 1.0925484305920792f*ux*uy*p2;
      Yb.y = 1.0925484305920792f*uy*uz*p2;
      Yb.z = 0.31539156525252005f*(3.f*z2-1.f)*p2;
      Yb.w = 1.0925484305920792f*ux*uz*p2;
      Yc.x = 0.5462742152960396f*(x2-y2)*p2;
      Yc.y = 0.5900435899266435f*uy*(3.f*x2-y2)*p3;
      Yc.z = 2.890611442640554f*ux*uy*uz*p3;
      Yc.w = 0.4570457994644658f*uy*(5.f*z2-1.f)*p3;
      Yd.x = 0.3731763325901154f*uz*(5.f*z2-3.f)*p3;
      Yd.y = 0.4570457994644658f*ux*(5.f*z2-1.f)*p3;
      Yd.z = 1.445305721320277f*uz*(x2-y2)*p3;
      Yd.w = 0.5900435899266435f*ux*(x2-3.f*y2)*p3;
      *reinterpret_cast<float4*>(&feat[t][0])  = Ya;
      *reinterpret_cast<float4*>(&feat[t][4])  = Yb;
      *reinterpret_cast<float4*>(&feat[t][8])  = Yc;
      *reinterpret_cast<float4*>(&feat[t][12]) = Yd;
    }
    __syncthreads();

    // ---- Phase 1: sv_n = sin((n+1)*th)/((n+1)*th + 1e-6), 2 lanes per edge, 12 n each ----
    {
      int c = t >> 1, h = t & 1;
      if (c < nc){
        float th = thlds[c];
        int nbase = h*12;
        #pragma unroll
        for (int k = 0; k < 12; ++k){
          int n = nbase + k;
          float sv = 0.f;
          if (n < 21){
            float arg = th * (float)(n+1);
            sv = __sinf(arg) * __builtin_amdgcn_rcpf(arg + 1e-6f);
          }
          feat[c][16+n] = sv;
        }
      }
    }
    __syncthreads();

    // ---- Phase 2: 62 lanes, 16 MACs/edge each: 1 b32 + 2 b128 LDS reads ----
    if (t < 62){
      for (int c = 0; c < nc; ++c){
        float yv = feat[c][yi];
        const float4 s4 = *reinterpret_cast<const float4*>(&feat[c][16+n0]);
        const float4 w4 = *reinterpret_cast<const float4*>(&feat[c][40]);
        float yr;
        yr = yv*s4.x;
        a0.x = fmaf(yr,w4.x,a0.x); a0.y = fmaf(yr,w4.y,a0.y);
        a0.z = fmaf(yr,w4.z,a0.z); a0.w = fmaf(yr,w4.w,a0.w);
        yr = yv*s4.y;
        a1.x = fmaf(yr,w4.x,a1.x); a1.y = fmaf(yr,w4.y,a1.y);
        a1.z = fmaf(yr,w4.z,a1.z); a1.w = fmaf(yr,w4.w,a1.w);
        yr = yv*s4.z;
        a2.x = fmaf(yr,w4.x,a2.x); a2.y = fmaf(yr,w4.y,a2.y);
        a2.z = fmaf(yr,w4.z,a2.z); a2.w = fmaf(yr,w4.w,a2.w);
        yr = yv*s4.w;
        a3.x = fmaf(yr,w4.x,a3.x); a3.y = fmaf(yr,w4.y,a3.y);
        a3.z = fmaf(yr,w4.z,a3.z); a3.w = fmaf(yr,w4.w,a3.w);
      }
    }
  }

  if (t < 62){
    float* o = out + (size_t)atom*OUTF + ob;
    *reinterpret_cast<float4*>(o) = a0;            // nvalid >= 1 always
    if (nvalid > 1) *reinterpret_cast<float4*>(o+4)  = a1;
    if (nvalid > 2) *reinterpret_cast<float4*>(o+8)  = a2;
    if (nvalid > 3) *reinterpret_cast<float4*>(o+12) = a3;
  }
}

extern "C" void kernel_launch(void* const* d_in, const int* in_sizes, int n_in,
                              void* d_out, int out_size, void* d_ws, size_t ws_size,
                              hipStream_t stream)
{
  const float* R  = (const float*)d_in[0];
  const int* seg  = (const int*)d_in[1];
  const int* Z    = (const int*)d_in[2];
  const float* W  = (const float*)d_in[3];
  float* out = (float*)d_out;

  int P = in_sizes[0] / 3;
  int A = out_size / OUTF;

  int* counts  = (int*)d_ws;
  int* offsets = counts + A;
  int* cursor  = offsets + A;
  int* sorted  = cursor + A;

  hipMemsetAsync(counts, 0, (size_t)A*sizeof(int), stream);
  count_k<<<(P + 255)/256, 256, 0, stream>>>(seg, P, counts);
  scan_k<<<1, 1024, 0, stream>>>(counts, A, offsets, cursor);
  scatter_k<<<(P + 255)/256, 256, 0, stream>>>(seg, P, cursor, sorted);
  accum_k<<<A, 64, 0, stream>>>(R, Z, W, sorted, offsets, counts, out);
}

// Round 3
// 67.430 us; speedup vs baseline: 2.0591x; 1.0088x over previous
//
#include <hip/hip_runtime.h>
#include <math.h>

constexpr float CUT = 5.0f;
constexpr float PI_F = 3.14159265358979323846f;
constexpr int OUTF = 936;
constexpr int ECH = 32;   // edges per chunk
constexpr int FR  = 44;   // feat row stride: [0..15]=Y', [16..36]=sv, [40..43]=w

__global__ void zero_k(int* __restrict__ counts, int A){
  int t = blockIdx.x*blockDim.x + threadIdx.x;
  if (t < A) counts[t] = 0;
}

__global__ void count_k(const int* __restrict__ seg, int P, int* __restrict__ counts){
  int p = blockIdx.x*blockDim.x + threadIdx.x;
  if (p < P) atomicAdd(&counts[seg[p]], 1);
}

// Single-block exclusive scan over A counts -> offsets (and working copy in cursor).
__global__ __launch_bounds__(1024) void scan_k(const int* __restrict__ counts, int A,
                                               int* __restrict__ offsets, int* __restrict__ cursor){
  __shared__ int sums[1024];
  int t = threadIdx.x;
  int per = (A + 1023) >> 10;
  int base = t * per;
  int local[32];
  int s = 0;
  #pragma unroll
  for (int k = 0; k < 32; ++k){
    if (k < per){
      int c = (base + k < A) ? counts[base + k] : 0;
      local[k] = s; s += c;
    }
  }
  sums[t] = s;
  __syncthreads();
  for (int off = 1; off < 1024; off <<= 1){
    int v = (t >= off) ? sums[t - off] : 0;
    __syncthreads();
    sums[t] += v;
    __syncthreads();
  }
  int excl = (t == 0) ? 0 : sums[t-1];
  #pragma unroll
  for (int k = 0; k < 32; ++k){
    if (k < per && base + k < A){
      int o = excl + local[k];
      offsets[base+k] = o;
      cursor[base+k]  = o;
    }
  }
}

// Scatter full per-edge payload to sorted position:
//   payload[2*pos]   = (rx, ry, rz, th)   th = d*pi/CUT
//   payload[2*pos+1] = W_species[Z[p]]
__global__ void scatter_k(const int* __restrict__ seg, const float* __restrict__ R,
                          const int* __restrict__ Z, const float* __restrict__ W,
                          int P, int* __restrict__ cursor, float4* __restrict__ payload){
  int p = blockIdx.x*blockDim.x + threadIdx.x;
  if (p < P){
    int a = seg[p];
    int pos = atomicAdd(&cursor[a], 1);
    float rx = R[3*p], ry = R[3*p+1], rz = R[3*p+2];
    float d = sqrtf(fmaf(rx,rx, fmaf(ry,ry, rz*rz)) + 1e-12f);
    float th = d * (PI_F/CUT);
    int z = Z[p];
    float4 w = *reinterpret_cast<const float4*>(W + 4*z);
    payload[2*pos]   = make_float4(rx, ry, rz, th);
    payload[2*pos+1] = w;
  }
}

__global__ __launch_bounds__(64) void accum_k(
    const float4* __restrict__ payload,
    const int* __restrict__ offsets, const int* __restrict__ counts,
    float* __restrict__ out)
{
  int atom = blockIdx.x;
  int t = threadIdx.x;
  int start = offsets[atom];
  int cnt = counts[atom];

  __shared__ float feat[ECH][FR];

  // Thread -> (l, m, n0): each active thread owns 4 consecutive n of one m, all 4 s.
  int yi = 0, n0 = 0, ob = 0, nvalid = 0;
  if (t < 62){
    int l, m, r;
    if (t < 6){       l = 0; m = 0;      n0 = 4*t; }
    else if (t < 21){ l = 1; r = t-6;  m = r/5; n0 = 4*(r-5*m); }
    else if (t < 41){ l = 2; r = t-21; m = r/4; n0 = 4*(r-4*m); }
    else {            l = 3; r = t-41; m = r/3; n0 = 4*(r-3*m); }
    const int NLa[4] = {21,18,15,12};
    const int YBa[4] = {0,1,4,9};
    const int OBa[4] = {0,84,300,600};
    int nl = NLa[l];
    yi = YBa[l] + m;
    ob = OBa[l] + (m*nl + n0)*4;
    nvalid = min(4, nl - n0);
  }

  float4 a0 = make_float4(0.f,0.f,0.f,0.f), a1 = a0, a2 = a0, a3 = a0;

  for (int c0 = 0; c0 < cnt; c0 += ECH){
    int nc = min(ECH, cnt - c0);
    __syncthreads();   // WAR: previous phase-2 reads vs this chunk's LDS writes

    // ---- Phase 0 (lanes 0..nc-1): coalesced payload load, scaled Y + w into LDS ----
    if (t < nc){
      float4 rt = payload[2*(start + c0 + t)];
      float4 w4 = payload[2*(start + c0 + t) + 1];
      float th = rt.w;
      float d  = th * (CUT/PI_F);
      float inv = __builtin_amdgcn_rcpf(d);
      float ux = rt.x*inv, uy = rt.y*inv, uz = rt.z*inv;
      float fc = 0.5f*__cosf(fminf(th, PI_F)) + 0.5f;
      float b  = th * (1.0f/PI_F);              // d/CUT
      float p1 = fc*b, p2 = p1*b, p3 = p2*b;
      float x2 = ux*ux, y2 = uy*uy, z2 = uz*uz;
      float4 Ya, Yb, Yc, Yd;
      Ya.x = 0.28209479177387814f*fc;
      Ya.y = 0.4886025119029199f*uy*p1;
      Ya.z = 0.4886025119029199f*uz*p1;
      Ya.w = 0.4886025119029199f*ux*p1;
      Yb.x = 1.0925484305920792f*ux*uy*p2;
      Yb.y = 1.0925484305920792f*uy*uz*p2;
      Yb.z = 0.31539156525252005f*(3.f*z2-1.f)*p2;
      Yb.w = 1.0925484305920792f*ux*uz*p2;
      Yc.x = 0.5462742152960396f*(x2-y2)*p2;
      Yc.y = 0.5900435899266435f*uy*(3.f*x2-y2)*p3;
      Yc.z = 2.890611442640554f*ux*uy*uz*p3;
      Yc.w = 0.4570457994644658f*uy*(5.f*z2-1.f)*p3;
      Yd.x = 0.3731763325901154f*uz*(5.f*z2-3.f)*p3;
      Yd.y = 0.4570457994644658f*ux*(5.f*z2-1.f)*p3;
      Yd.z = 1.445305721320277f*uz*(x2-y2)*p3;
      Yd.w = 0.5900435899266435f*ux*(x2-3.f*y2)*p3;
      *reinterpret_cast<float4*>(&feat[t][0])  = Ya;
      *reinterpret_cast<float4*>(&feat[t][4])  = Yb;
      *reinterpret_cast<float4*>(&feat[t][8])  = Yc;
      *reinterpret_cast<float4*>(&feat[t][12]) = Yd;
      *reinterpret_cast<float4*>(&feat[t][40]) = w4;
    }

    // ---- Phase 1 (2 lanes/edge): sv_n = sin((n+1)th)/((n+1)th+1e-6), th from payload ----
    {
      int c = t >> 1, h = t & 1;
      if (c < nc){
        float th = reinterpret_cast<const float*>(payload)[8*(start + c0 + c) + 3];
        #pragma unroll
        for (int k = 0; k < 11; ++k){
          int n = h*11 + k;
          if (n < 21){
            float arg = th * (float)(n+1);
            feat[c][16+n] = __sinf(arg) * __builtin_amdgcn_rcpf(arg + 1e-6f);
          }
        }
      }
    }
    __syncthreads();

    // ---- Phase 2: 62 lanes, 16 MACs/edge: 1 b32 + 2 b128 LDS reads ----
    if (t < 62){
      for (int c = 0; c < nc; ++c){
        float yv = feat[c][yi];
        const float4 s4 = *reinterpret_cast<const float4*>(&feat[c][16+n0]);
        const float4 w4 = *reinterpret_cast<const float4*>(&feat[c][40]);
        float yr;
        yr = yv*s4.x;
        a0.x = fmaf(yr,w4.x,a0.x); a0.y = fmaf(yr,w4.y,a0.y);
        a0.z = fmaf(yr,w4.z,a0.z); a0.w = fmaf(yr,w4.w,a0.w);
        yr = yv*s4.y;
        a1.x = fmaf(yr,w4.x,a1.x); a1.y = fmaf(yr,w4.y,a1.y);
        a1.z = fmaf(yr,w4.z,a1.z); a1.w = fmaf(yr,w4.w,a1.w);
        yr = yv*s4.z;
        a2.x = fmaf(yr,w4.x,a2.x); a2.y = fmaf(yr,w4.y,a2.y);
        a2.z = fmaf(yr,w4.z,a2.z); a2.w = fmaf(yr,w4.w,a2.w);
        yr = yv*s4.w;
        a3.x = fmaf(yr,w4.x,a3.x); a3.y = fmaf(yr,w4.y,a3.y);
        a3.z = fmaf(yr,w4.z,a3.z); a3.w = fmaf(yr,w4.w,a3.w);
      }
    }
  }

  if (t < 62){
    float* o = out + (size_t)atom*OUTF + ob;
    *reinterpret_cast<float4*>(o) = a0;
    if (nvalid > 1) *reinterpret_cast<float4*>(o+4)  = a1;
    if (nvalid > 2) *reinterpret_cast<float4*>(o+8)  = a2;
    if (nvalid > 3) *reinterpret_cast<float4*>(o+12) = a3;
  }
}

extern "C" void kernel_launch(void* const* d_in, const int* in_sizes, int n_in,
                              void* d_out, int out_size, void* d_ws, size_t ws_size,
                              hipStream_t stream)
{
  const float* R  = (const float*)d_in[0];
  const int* seg  = (const int*)d_in[1];
  const int* Z    = (const int*)d_in[2];
  const float* W  = (const float*)d_in[3];
  float* out = (float*)d_out;

  int P = in_sizes[0] / 3;
  int A = out_size / OUTF;

  int* counts  = (int*)d_ws;
  int* offsets = counts + A;
  int* cursor  = offsets + A;
  float4* payload = (float4*)((char*)d_ws + (size_t)3*A*sizeof(int));  // 3*A*4 is 16B-aligned for A=8192

  zero_k<<<(A + 255)/256, 256, 0, stream>>>(counts, A);
  count_k<<<(P + 255)/256, 256, 0, stream>>>(seg, P, counts);
  scan_k<<<1, 1024, 0, stream>>>(counts, A, offsets, cursor);
  scatter_k<<<(P + 255)/256, 256, 0, stream>>>(seg, R, Z, W, P, cursor, payload);
  accum_k<<<A, 64, 0, stream>>>(payload, offsets, counts, out);
}

// Round 4
// 44.397 us; speedup vs baseline: 3.1274x; 1.5188x over previous
//
#include <hip/hip_runtime.h>
#include <math.h>

constexpr float CUT = 5.0f;
constexpr float PI_F = 3.14159265358979323846f;
constexpr int OUTF = 936;
constexpr int ECH = 32;    // edges per chunk in accum
constexpr int FR  = 44;    // LDS feat row stride: [0..15]=Y', [16..36]=sv, [40..43]=w
constexpr int CAP = 96;    // payload slots per atom (counts ~Poisson(32); P(>96) ~ 0)
constexpr int OVF_CAP = 4096;

__global__ void zero_k(int* __restrict__ counts, int n){
  int t = blockIdx.x*blockDim.x + threadIdx.x;
  if (t < n) counts[t] = 0;
}

// One pass over edges: count + compute payload + scatter to fixed-capacity bin.
//   payload[2*(a*CAP+pos)]   = (rx, ry, rz, th)    th = d*pi/CUT
//   payload[2*(a*CAP+pos)+1] = W_species[Z[p]]
__global__ void bin_k(const int* __restrict__ seg, const float* __restrict__ R,
                      const int* __restrict__ Z, const float* __restrict__ W,
                      int P, int* __restrict__ counts,
                      int* __restrict__ ovfcnt, int* __restrict__ ovflist,
                      float4* __restrict__ payload){
  int p = blockIdx.x*blockDim.x + threadIdx.x;
  if (p >= P) return;
  int a = seg[p];
  int pos = atomicAdd(&counts[a], 1);
  if (pos < CAP){
    float rx = R[3*p], ry = R[3*p+1], rz = R[3*p+2];
    float d = sqrtf(fmaf(rx,rx, fmaf(ry,ry, rz*rz)) + 1e-12f);
    float th = d * (PI_F/CUT);
    float4 w = *reinterpret_cast<const float4*>(W + 4*Z[p]);
    size_t slot = (size_t)a*CAP + pos;
    payload[2*slot]   = make_float4(rx, ry, rz, th);
    payload[2*slot+1] = w;
  } else {
    int o = atomicAdd(ovfcnt, 1);
    if (o < OVF_CAP) ovflist[o] = p;
  }
}

__global__ __launch_bounds__(64) void accum_k(
    const float4* __restrict__ payload, const int* __restrict__ counts,
    float* __restrict__ out)
{
  int atom = blockIdx.x;
  int t = threadIdx.x;
  int cnt = min(counts[atom], CAP);
  int start = atom*CAP;

  __shared__ float feat[ECH][FR];

  // Thread -> (l, m, n0): each active thread owns 4 consecutive n of one m, all 4 s.
  int yi = 0, n0 = 0, ob = 0, nvalid = 0;
  if (t < 62){
    int l, m, r;
    if (t < 6){       l = 0; m = 0;      n0 = 4*t; }
    else if (t < 21){ l = 1; r = t-6;  m = r/5; n0 = 4*(r-5*m); }
    else if (t < 41){ l = 2; r = t-21; m = r/4; n0 = 4*(r-4*m); }
    else {            l = 3; r = t-41; m = r/3; n0 = 4*(r-3*m); }
    const int NLa[4] = {21,18,15,12};
    const int YBa[4] = {0,1,4,9};
    const int OBa[4] = {0,84,300,600};
    int nl = NLa[l];
    yi = YBa[l] + m;
    ob = OBa[l] + (m*nl + n0)*4;
    nvalid = min(4, nl - n0);
  }

  float4 a0 = make_float4(0.f,0.f,0.f,0.f), a1 = a0, a2 = a0, a3 = a0;

  for (int c0 = 0; c0 < cnt; c0 += ECH){
    int nc = min(ECH, cnt - c0);
    __syncthreads();   // WAR: previous phase-2 reads vs this chunk's LDS writes

    // ---- Phase 0 (lanes 0..nc-1): coalesced payload load, scaled Y + w into LDS ----
    if (t < nc){
      float4 rt = payload[2*(start + c0 + t)];
      float4 w4 = payload[2*(start + c0 + t) + 1];
      float th = rt.w;
      float d  = th * (CUT/PI_F);
      float inv = __builtin_amdgcn_rcpf(d);
      float ux = rt.x*inv, uy = rt.y*inv, uz = rt.z*inv;
      float fc = 0.5f*__cosf(fminf(th, PI_F)) + 0.5f;
      float b  = th * (1.0f/PI_F);              // d/CUT
      float p1 = fc*b, p2 = p1*b, p3 = p2*b;
      float x2 = ux*ux, y2 = uy*uy, z2 = uz*uz;
      float4 Ya, Yb, Yc, Yd;
      Ya.x = 0.28209479177387814f*fc;
      Ya.y = 0.4886025119029199f*uy*p1;
      Ya.z = 0.4886025119029199f*uz*p1;
      Ya.w = 0.4886025119029199f*ux*p1;
      Yb.x = 1.0925484305920792f*ux*uy*p2;
      Yb.y = 1.0925484305920792f*uy*uz*p2;
      Yb.z = 0.31539156525252005f*(3.f*z2-1.f)*p2;
      Yb.w = 1.0925484305920792f*ux*uz*p2;
      Yc.x = 0.5462742152960396f*(x2-y2)*p2;
      Yc.y = 0.5900435899266435f*uy*(3.f*x2-y2)*p3;
      Yc.z = 2.890611442640554f*ux*uy*uz*p3;
      Yc.w = 0.4570457994644658f*uy*(5.f*z2-1.f)*p3;
      Yd.x = 0.3731763325901154f*uz*(5.f*z2-3.f)*p3;
      Yd.y = 0.4570457994644658f*ux*(5.f*z2-1.f)*p3;
      Yd.z = 1.445305721320277f*uz*(x2-y2)*p3;
      Yd.w = 0.5900435899266435f*ux*(x2-3.f*y2)*p3;
      *reinterpret_cast<float4*>(&feat[t][0])  = Ya;
      *reinterpret_cast<float4*>(&feat[t][4])  = Yb;
      *reinterpret_cast<float4*>(&feat[t][8])  = Yc;
      *reinterpret_cast<float4*>(&feat[t][12]) = Yd;
      *reinterpret_cast<float4*>(&feat[t][40]) = w4;
    }

    // ---- Phase 1 (2 lanes/edge): sv_n = sin((n+1)th)/((n+1)th+1e-6) ----
    {
      int c = t >> 1, h = t & 1;
      if (c < nc){
        float th = reinterpret_cast<const float*>(payload)[8*(start + c0 + c) + 3];
        #pragma unroll
        for (int k = 0; k < 11; ++k){
          int n = h*11 + k;
          if (n < 21){
            float arg = th * (float)(n+1);
            feat[c][16+n] = __sinf(arg) * __builtin_amdgcn_rcpf(arg + 1e-6f);
          }
        }
      }
    }
    __syncthreads();

    // ---- Phase 2: 62 lanes, 16 MACs/edge: 1 b32 + 2 b128 LDS reads ----
    if (t < 62){
      for (int c = 0; c < nc; ++c){
        float yv = feat[c][yi];
        const float4 s4 = *reinterpret_cast<const float4*>(&feat[c][16+n0]);
        const float4 w4 = *reinterpret_cast<const float4*>(&feat[c][40]);
        float yr;
        yr = yv*s4.x;
        a0.x = fmaf(yr,w4.x,a0.x); a0.y = fmaf(yr,w4.y,a0.y);
        a0.z = fmaf(yr,w4.z,a0.z); a0.w = fmaf(yr,w4.w,a0.w);
        yr = yv*s4.y;
        a1.x = fmaf(yr,w4.x,a1.x); a1.y = fmaf(yr,w4.y,a1.y);
        a1.z = fmaf(yr,w4.z,a1.z); a1.w = fmaf(yr,w4.w,a1.w);
        yr = yv*s4.z;
        a2.x = fmaf(yr,w4.x,a2.x); a2.y = fmaf(yr,w4.y,a2.y);
        a2.z = fmaf(yr,w4.z,a2.z); a2.w = fmaf(yr,w4.w,a2.w);
        yr = yv*s4.w;
        a3.x = fmaf(yr,w4.x,a3.x); a3.y = fmaf(yr,w4.y,a3.y);
        a3.z = fmaf(yr,w4.z,a3.z); a3.w = fmaf(yr,w4.w,a3.w);
      }
    }
  }

  if (t < 62){
    float* o = out + (size_t)atom*OUTF + ob;
    *reinterpret_cast<float4*>(o) = a0;
    if (nvalid > 1) *reinterpret_cast<float4*>(o+4)  = a1;
    if (nvalid > 2) *reinterpret_cast<float4*>(o+8)  = a2;
    if (nvalid > 3) *reinterpret_cast<float4*>(o+12) = a3;
  }
}

// Safety net for bin overflow (never executes for this input): direct atomic adds.
__global__ __launch_bounds__(256) void fixup_k(
    const int* __restrict__ seg, const float* __restrict__ R,
    const int* __restrict__ Z, const float* __restrict__ W,
    const int* __restrict__ ovfcnt, const int* __restrict__ ovflist,
    float* __restrict__ out)
{
  int n = min(*ovfcnt, OVF_CAP);
  for (int i = threadIdx.x; i < n; i += 256){
    int p = ovflist[i];
    int a = seg[p];
    float rx = R[3*p], ry = R[3*p+1], rz = R[3*p+2];
    float d = sqrtf(fmaf(rx,rx, fmaf(ry,ry, rz*rz)) + 1e-12f);
    float inv = 1.0f/d;
    float ux = rx*inv, uy = ry*inv, uz = rz*inv;
    float th = d * (PI_F/CUT);
    float fc = 0.5f*cosf(fminf(th, PI_F)) + 0.5f;
    float b = d*(1.0f/CUT);
    float p1 = fc*b, p2 = p1*b, p3 = p2*b;
    float x2 = ux*ux, y2 = uy*uy, z2 = uz*uz;
    float Y[16];
    Y[0] = 0.28209479177387814f*fc;
    Y[1] = 0.4886025119029199f*uy*p1;
    Y[2] = 0.4886025119029199f*uz*p1;
    Y[3] = 0.4886025119029199f*ux*p1;
    Y[4] = 1.0925484305920792f*ux*uy*p2;
    Y[5] = 1.0925484305920792f*uy*uz*p2;
    Y[6] = 0.31539156525252005f*(3.f*z2-1.f)*p2;
    Y[7] = 1.0925484305920792f*ux*uz*p2;
    Y[8] = 0.5462742152960396f*(x2-y2)*p2;
    Y[9] = 0.5900435899266435f*uy*(3.f*x2-y2)*p3;
    Y[10]= 2.890611442640554f*ux*uy*uz*p3;
    Y[11]= 0.4570457994644658f*uy*(5.f*z2-1.f)*p3;
    Y[12]= 0.3731763325901154f*uz*(5.f*z2-3.f)*p3;
    Y[13]= 0.4570457994644658f*ux*(5.f*z2-1.f)*p3;
    Y[14]= 1.445305721320277f*uz*(x2-y2)*p3;
    Y[15]= 0.5900435899266435f*ux*(x2-3.f*y2)*p3;
    float sv[21];
    for (int nn = 0; nn < 21; ++nn){
      float arg = th*(float)(nn+1);
      sv[nn] = sinf(arg)/(arg + 1e-6f);
    }
    const float* w = W + 4*Z[p];
    const int NLa[4] = {21,18,15,12};
    const int YBa[4] = {0,1,4,9};
    const int OBa[4] = {0,84,300,600};
    float* orow = out + (size_t)a*OUTF;
    for (int l = 0; l < 4; ++l){
      for (int m = 0; m < 2*l+1; ++m){
        float yv = Y[YBa[l]+m];
        for (int nn = 0; nn < NLa[l]; ++nn){
          float yr = yv*sv[nn];
          int off = OBa[l] + (m*NLa[l]+nn)*4;
          for (int s = 0; s < 4; ++s)
            atomicAdd(orow + off + s, yr*w[s]);
        }
      }
    }
  }
}

extern "C" void kernel_launch(void* const* d_in, const int* in_sizes, int n_in,
                              void* d_out, int out_size, void* d_ws, size_t ws_size,
                              hipStream_t stream)
{
  const float* R  = (const float*)d_in[0];
  const int* seg  = (const int*)d_in[1];
  const int* Z    = (const int*)d_in[2];
  const float* W  = (const float*)d_in[3];
  float* out = (float*)d_out;

  int P = in_sizes[0] / 3;
  int A = out_size / OUTF;

  int* counts  = (int*)d_ws;                       // A ints
  int* ovfcnt  = counts + A;                       // 1 int
  int* ovflist = ovfcnt + 1;                       // OVF_CAP ints
  float4* payload = (float4*)((char*)d_ws + 65536); // A*CAP*32 B, 16B-aligned

  zero_k<<<(A + 1 + 255)/256, 256, 0, stream>>>(counts, A + 1);
  bin_k<<<(P + 255)/256, 256, 0, stream>>>(seg, R, Z, W, P, counts, ovfcnt, ovflist, payload);
  accum_k<<<A, 64, 0, stream>>>(payload, counts, out);
  fixup_k<<<1, 256, 0, stream>>>(seg, R, Z, W, ovfcnt, ovflist, out);
}